// Round 9
// baseline (2010.685 us; speedup 1.0000x reference)
//
#include <hip/hip_runtime.h>

#define KK 64
#define TT 1024
#define BB 256
#define NCH 16         // chunks per sequence
#define SS  64         // steps per chunk (NCH*SS = 1024; t=1..1023 real, t=1024 masked)

typedef float  f32x4  __attribute__((ext_vector_type(4)));
typedef short  bf16x4 __attribute__((ext_vector_type(4)));

// truncate-pack two fp32 -> bf16 pair (low16 = bf16(lo)): single v_perm
__device__ __forceinline__ unsigned bf16pair_t(float lo, float hi) {
    return __builtin_amdgcn_perm(__float_as_uint(hi), __float_as_uint(lo), 0x07060302u);
}
// rounded pack (constant A-fragments, once)
__device__ __forceinline__ unsigned bf16pair_r(float lo, float hi) {
    unsigned l = __float_as_uint(lo) + 0x8000u;
    unsigned h = __float_as_uint(hi) + 0x8000u;
    return __builtin_amdgcn_perm(h, l, 0x07060302u);
}

__device__ __forceinline__ f32x4 mfma16(bf16x4 a, bf16x4 b, f32x4 c) {
#if __has_builtin(__builtin_amdgcn_mfma_f32_16x16x16_bf16)
    return __builtin_amdgcn_mfma_f32_16x16x16_bf16(a, b, c, 0, 0, 0);
#else
    return __builtin_amdgcn_mfma_f32_16x16x16bf16_1k(a, b, c, 0, 0, 0);
#endif
}

// ---------------------------------------------------------------------------
// Phase 1 (time-parallel): per (batch, chunk) wave computes
//   P = prod_{t in chunk, mask[t]!=0} diag(exp(feat_t)) * exp(trans)
// 4096 independent waves -> real occupancy, latencies hidden by TLP.
// In-wave product uses the r8-verified K=16 register coincidence per column
// tile nt: B-frag for K-chunk c packs directly from the D-accumulator regs.
// State: aP[nt][4c+r] = P[16c+4q+r][16nt+nc]. Row-scale by emissions applies
// to D rows (em[mt][r] = exp(feats[t][16mt+4q+r]) — quad-indexed broadcast).
// Global renorm every 4 multiplies (scalar factors out of the product).
// Masked step == multiply by I == skip (exact; wave-uniform via 64-bit ballot).
// ---------------------------------------------------------------------------
__global__ __launch_bounds__(64)
__attribute__((amdgpu_waves_per_eu(2, 2)))
void crf_scan_chunks(const float* __restrict__ feats,
                     const float* __restrict__ trans,
                     const float* __restrict__ masks,
                     unsigned short* __restrict__ wsP,
                     float* __restrict__ wsOff)
{
    const int blk = blockIdx.x;
    const int b = blk >> 4, ch = blk & (NCH - 1);
    const int L = threadIdx.x, nc = L & 15, q = L >> 4;

    // constant A-frags: bf16(exp(trans[16mt+nc][16c+4q+j])) — r8-verified layout
    uint2 afr[4][4];
    #pragma unroll
    for (int mt = 0; mt < 4; ++mt)
        #pragma unroll
        for (int c = 0; c < 4; ++c) {
            const float* tp = trans + (16 * mt + nc) * KK + 16 * c + 4 * q;
            float4 x = *(const float4*)tp;
            afr[mt][c] = make_uint2(bf16pair_r(__expf(x.x), __expf(x.y)),
                                    bf16pair_r(__expf(x.z), __expf(x.w)));
            asm volatile("" : "+v"(afr[mt][c].x), "+v"(afr[mt][c].y));
        }

    // P = I : aP[nt][4c+r]=1 iff 16c+4q+r == 16nt+nc  (c==nt, 4q+r==nc)
    float aP[4][16];
    #pragma unroll
    for (int nt = 0; nt < 4; ++nt)
        #pragma unroll
        for (int k = 0; k < 16; ++k) aP[nt][k] = 0.f;
    if (q == (nc >> 2)) {
        #pragma unroll
        for (int nt = 0; nt < 4; ++nt) aP[nt][4 * nt + (nc & 3)] = 1.f;
    }
    float offset = 0.f;

    const float* fb = feats + (size_t)b * TT * KK;
    const float* mp = masks + (size_t)b * TT;

    // per-chunk mask bits (wave-uniform per step): bit u = step t=ch*64+1+u live
    int tL = ch * SS + 1 + L;
    bool okb = (tL < TT) && (mp[tL < TT ? tL : 0] != 0.f);
    unsigned long long bits = __ballot(okb);

    for (int u0 = 0; u0 < SS; u0 += 4) {
        #pragma unroll
        for (int v = 0; v < 4; ++v) {
            int u = u0 + v;
            if (!((bits >> u) & 1ull)) continue;   // masked step == identity

            const float* fp = fb + (size_t)(ch * SS + 1 + u) * KK + 4 * q;
            float4 x0 = *(const float4*)(fp);
            float4 x1 = *(const float4*)(fp + 16);
            float4 x2 = *(const float4*)(fp + 32);
            float4 x3 = *(const float4*)(fp + 48);
            float em[4][4];
            em[0][0]=__expf(x0.x); em[0][1]=__expf(x0.y); em[0][2]=__expf(x0.z); em[0][3]=__expf(x0.w);
            em[1][0]=__expf(x1.x); em[1][1]=__expf(x1.y); em[1][2]=__expf(x1.z); em[1][3]=__expf(x1.w);
            em[2][0]=__expf(x2.x); em[2][1]=__expf(x2.y); em[2][2]=__expf(x2.z); em[2][3]=__expf(x2.w);
            em[3][0]=__expf(x3.x); em[3][1]=__expf(x3.y); em[3][2]=__expf(x3.z); em[3][3]=__expf(x3.w);

            #pragma unroll
            for (int nt = 0; nt < 4; ++nt) {
                bf16x4 bfr[4];
                #pragma unroll
                for (int c = 0; c < 4; ++c) {
                    uint2 w = make_uint2(bf16pair_t(aP[nt][4*c+0], aP[nt][4*c+1]),
                                         bf16pair_t(aP[nt][4*c+2], aP[nt][4*c+3]));
                    bfr[c] = *(bf16x4*)&w;
                }
                f32x4 acc[4];
                #pragma unroll
                for (int mt = 0; mt < 4; ++mt) acc[mt] = (f32x4){0.f, 0.f, 0.f, 0.f};
                #pragma unroll
                for (int c = 0; c < 4; ++c)
                    #pragma unroll
                    for (int mt = 0; mt < 4; ++mt)
                        acc[mt] = mfma16(*(bf16x4*)&afr[mt][c], bfr[c], acc[mt]);
                #pragma unroll
                for (int mt = 0; mt < 4; ++mt)
                    #pragma unroll
                    for (int r = 0; r < 4; ++r)
                        aP[nt][4*mt + r] = acc[mt][r] * em[mt][r];
            }
        }

        // global renorm (uniform scalar factors out of the product)
        float cmx = aP[0][0];
        #pragma unroll
        for (int nt = 0; nt < 4; ++nt)
            #pragma unroll
            for (int k = 0; k < 16; ++k) cmx = fmaxf(cmx, aP[nt][k]);
        #pragma unroll
        for (int off = 1; off <= 32; off <<= 1)
            cmx = fmaxf(cmx, __shfl_xor(cmx, off, 64));
        cmx = fmaxf(cmx, 1e-30f);
        float rc = __builtin_amdgcn_rcpf(cmx);
        #pragma unroll
        for (int nt = 0; nt < 4; ++nt)
            #pragma unroll
            for (int k = 0; k < 16; ++k) aP[nt][k] *= rc;
        offset += __logf(cmx);
    }

    // store P (bf16) in phase-2 A-frag order: [rowblk][colblk][m16][k16]
    unsigned short* Pp = wsP + ((size_t)blk << 12);
    #pragma unroll
    for (int rb = 0; rb < 4; ++rb)
        #pragma unroll
        for (int nt = 0; nt < 4; ++nt)
            #pragma unroll
            for (int r = 0; r < 4; ++r)
                Pp[(rb * 4 + nt) * 256 + (4 * q + r) * 16 + nc] =
                    (unsigned short)(__float_as_uint(aP[nt][4 * rb + r]) >> 16);
    if (L == 0) wsOff[blk] = offset;
}

// ---------------------------------------------------------------------------
// Phase 2: per batch wave, 16 serial chunk-matvecs alpha <- P_ch * alpha.
// A-frags loaded per chunk (prefetched 1 ahead); alpha replicated across the
// 16 n-columns so the r8 pack coincidence applies unchanged. Gold score fused.
// ---------------------------------------------------------------------------
__global__ __launch_bounds__(64)
__attribute__((amdgpu_waves_per_eu(1, 1)))
void crf_combine(const unsigned short* __restrict__ wsP,
                 const float* __restrict__ wsOff,
                 const float* __restrict__ feats,
                 const float* __restrict__ trans,
                 const int*   __restrict__ tags,
                 const float* __restrict__ masks,
                 float* __restrict__ out)
{
    const int b = blockIdx.x;
    const int L = threadIdx.x, nc = L & 15, q = L >> 4;
    const unsigned short* Pb = wsP + ((size_t)(b * NCH) << 12);

    float aD[16];
    #pragma unroll
    for (int k = 0; k < 16; ++k) aD[k] = 0.f;
    if (q == 0) aD[0] = 1.f;           // alpha0 = delta(START), all columns
    float offset = 0.f;

    uint2 fr[16];
    #pragma unroll
    for (int i = 0; i < 16; ++i)
        fr[i] = *(const uint2*)(Pb + i * 256 + nc * 16 + 4 * q);

    for (int ch = 0; ch < NCH; ++ch) {
        uint2 nf[16];
        const unsigned short* Pn = Pb + ((size_t)(ch + 1 < NCH ? ch + 1 : ch) << 12);
        #pragma unroll
        for (int i = 0; i < 16; ++i)
            nf[i] = *(const uint2*)(Pn + i * 256 + nc * 16 + 4 * q);

        bf16x4 bfv[4];
        #pragma unroll
        for (int c = 0; c < 4; ++c) {
            uint2 w = make_uint2(bf16pair_t(aD[4*c+0], aD[4*c+1]),
                                 bf16pair_t(aD[4*c+2], aD[4*c+3]));
            bfv[c] = *(bf16x4*)&w;
        }
        f32x4 acc[4];
        #pragma unroll
        for (int mt = 0; mt < 4; ++mt) acc[mt] = (f32x4){0.f, 0.f, 0.f, 0.f};
        #pragma unroll
        for (int c = 0; c < 4; ++c)
            #pragma unroll
            for (int mt = 0; mt < 4; ++mt)
                acc[mt] = mfma16(*(bf16x4*)&fr[mt * 4 + c], bfv[c], acc[mt]);

        float mx = acc[0][0];
        #pragma unroll
        for (int k = 1; k < 16; ++k) mx = fmaxf(mx, acc[k >> 2][k & 3]);
        mx = fmaxf(mx, __shfl_xor(mx, 16, 64));
        mx = fmaxf(mx, __shfl_xor(mx, 32, 64));
        mx = fmaxf(mx, 1e-30f);
        float rc = __builtin_amdgcn_rcpf(mx);
        #pragma unroll
        for (int k = 0; k < 16; ++k) aD[k] = acc[k >> 2][k & 3] * rc;
        offset += __logf(mx);

        #pragma unroll
        for (int i = 0; i < 16; ++i) fr[i] = nf[i];
    }

    // add phase-1 chunk offsets
    float ov = (L < NCH) ? wsOff[b * NCH + L] : 0.f;
    #pragma unroll
    for (int off = 1; off <= 32; off <<= 1) ov += __shfl_xor(ov, off, 64);
    offset += ov;

    // fwd = offset + log(sum_m alpha[m])
    float s = aD[0];
    #pragma unroll
    for (int k = 1; k < 16; ++k) s += aD[k];
    s += __shfl_xor(s, 16, 64);
    s += __shfl_xor(s, 32, 64);
    float fwd = offset + __logf(s);

    // fused gold score (r6-verified)
    const int*   tg = tags  + b * TT;
    const float* fb = feats + (size_t)b * TT * KK;
    const float* mp = masks + (size_t)b * TT;
    float g = 0.f;
    for (int t = 1 + L; t < TT; t += 64) {
        int ct = tg[t], pt = tg[t - 1];
        g += (trans[ct * KK + pt] + fb[(size_t)t * KK + ct]) * mp[t];
    }
    #pragma unroll
    for (int off = 1; off <= 32; off <<= 1) g += __shfl_xor(g, off, 64);

    if (L == 0) atomicAdd(out, (fwd - g) * (1.0f / (float)BB));
}

extern "C" void kernel_launch(void* const* d_in, const int* in_sizes, int n_in,
                              void* d_out, int out_size, void* d_ws, size_t ws_size,
                              hipStream_t stream) {
    const float* feats = (const float*)d_in[0];
    const float* trans = (const float*)d_in[1];
    const int*   tags  = (const int*)d_in[2];
    const float* masks = (const float*)d_in[3];
    float* out = (float*)d_out;

    unsigned short* wsP = (unsigned short*)d_ws;                 // 4096 chunks x 4096 bf16 = 33.5 MB
    float* wsOff = (float*)(wsP + ((size_t)BB * NCH << 12));     // 16 KB

    hipMemsetAsync(out, 0, sizeof(float), stream);
    crf_scan_chunks<<<BB * NCH, 64, 0, stream>>>(feats, trans, masks, wsP, wsOff);
    crf_combine<<<BB, 64, 0, stream>>>(wsP, wsOff, feats, trans, tags, masks, out);
}

// Round 10
// 460.062 us; speedup vs baseline: 4.3705x; 4.3705x over previous
//
#include <hip/hip_runtime.h>

#define KK 64
#define TT 1024
#define BB 256
#define NCH 16         // chunks per sequence
#define SS  64         // steps per chunk

typedef float  f32x4  __attribute__((ext_vector_type(4)));
typedef short  bf16x4 __attribute__((ext_vector_type(4)));

// truncate-pack two fp32 -> bf16 pair (low16 = bf16(lo)): single v_perm
__device__ __forceinline__ unsigned bf16pair_t(float lo, float hi) {
    return __builtin_amdgcn_perm(__float_as_uint(hi), __float_as_uint(lo), 0x07060302u);
}
__device__ __forceinline__ unsigned bf16pair_r(float lo, float hi) {
    unsigned l = __float_as_uint(lo) + 0x8000u;
    unsigned h = __float_as_uint(hi) + 0x8000u;
    return __builtin_amdgcn_perm(h, l, 0x07060302u);
}
// build bf16x4 fragments WITHOUT taking any address (keeps SROA alive;
// r9's *(bf16x4*)&arr[i] pattern pushed state into LDS -> 1e9 bank conflicts)
__device__ __forceinline__ bf16x4 packT(float a, float b, float c, float d) {
    uint2 u = make_uint2(bf16pair_t(a, b), bf16pair_t(c, d));
    return __builtin_bit_cast(bf16x4, u);
}
__device__ __forceinline__ bf16x4 packR(float a, float b, float c, float d) {
    uint2 u = make_uint2(bf16pair_r(a, b), bf16pair_r(c, d));
    return __builtin_bit_cast(bf16x4, u);
}

__device__ __forceinline__ f32x4 mfma16(bf16x4 a, bf16x4 b, f32x4 c) {
#if __has_builtin(__builtin_amdgcn_mfma_f32_16x16x16_bf16)
    return __builtin_amdgcn_mfma_f32_16x16x16_bf16(a, b, c, 0, 0, 0);
#else
    return __builtin_amdgcn_mfma_f32_16x16x16bf16_1k(a, b, c, 0, 0, 0);
#endif
}

// ---------------------------------------------------------------------------
// Phase 1 (time-parallel): block (b,ch) of 4 waves; wave w computes the
// 64x16 column-slice S = P_ch[:, 16w .. 16w+15], where
//   P_ch = prod_{t in chunk, mask!=0} diag(exp(feat_t)) * exp(trans).
// Per-wave state aD[16] (r8-proven register shape; no LDS). Each column j
// gets its own renorm offset o_j (stored per column, folded in phase 2).
// Masked step == identity == skip (wave-uniform via 64-bit ballot).
// ---------------------------------------------------------------------------
__global__ __launch_bounds__(256)
__attribute__((amdgpu_waves_per_eu(2, 2)))
void crf_scan(const float* __restrict__ feats,
              const float* __restrict__ trans,
              const float* __restrict__ masks,
              unsigned short* __restrict__ wsP,
              float* __restrict__ wsO)
{
    const int blk = blockIdx.x;            // b*NCH + ch
    const int b = blk >> 4, ch = blk & (NCH - 1);
    const int tid = threadIdx.x;
    const int w = tid >> 6;                // wave index = column tile
    const int L = tid & 63, nc = L & 15, q = L >> 4;

    // A-frags: bf16(exp(trans[16mt+nc][16c+4q+j])) — r8-verified layout
    bf16x4 afr[4][4];
    #pragma unroll
    for (int mt = 0; mt < 4; ++mt)
        #pragma unroll
        for (int c = 0; c < 4; ++c) {
            const float* tp = trans + (16 * mt + nc) * KK + 16 * c + 4 * q;
            float4 x = *(const float4*)tp;
            afr[mt][c] = packR(__expf(x.x), __expf(x.y), __expf(x.z), __expf(x.w));
        }

    // S = I-slice: aD[4c+r] = 1 iff row 16c+4q+r == col 16w+nc
    float aD[16];
    #pragma unroll
    for (int k = 0; k < 16; ++k) aD[k] = 0.f;
    if (q == (nc >> 2)) aD[4 * w + (nc & 3)] = 1.f;
    float offs = 0.f;                      // per-column log-scale

    const float* fb = feats + (size_t)b * TT * KK;
    const float* mp = masks + (size_t)b * TT;

    int tL = ch * SS + 1 + L;
    bool okb = (tL < TT) && (mp[tL < TT ? tL : TT - 1] != 0.f);
    unsigned long long bits = __ballot(okb);

    for (int u0 = 0; u0 < SS; u0 += 4) {
        #pragma unroll
        for (int v = 0; v < 4; ++v) {
            int u = u0 + v;
            if (!((bits >> u) & 1ull)) continue;   // masked step == identity

            const float* fp = fb + (size_t)(ch * SS + 1 + u) * KK + 4 * q;
            float4 x0 = *(const float4*)(fp);
            float4 x1 = *(const float4*)(fp + 16);
            float4 x2 = *(const float4*)(fp + 32);
            float4 x3 = *(const float4*)(fp + 48);
            float em[16];
            em[0] =__expf(x0.x); em[1] =__expf(x0.y); em[2] =__expf(x0.z); em[3] =__expf(x0.w);
            em[4] =__expf(x1.x); em[5] =__expf(x1.y); em[6] =__expf(x1.z); em[7] =__expf(x1.w);
            em[8] =__expf(x2.x); em[9] =__expf(x2.y); em[10]=__expf(x2.z); em[11]=__expf(x2.w);
            em[12]=__expf(x3.x); em[13]=__expf(x3.y); em[14]=__expf(x3.z); em[15]=__expf(x3.w);

            bf16x4 bfv0 = packT(aD[0],  aD[1],  aD[2],  aD[3]);
            bf16x4 bfv1 = packT(aD[4],  aD[5],  aD[6],  aD[7]);
            bf16x4 bfv2 = packT(aD[8],  aD[9],  aD[10], aD[11]);
            bf16x4 bfv3 = packT(aD[12], aD[13], aD[14], aD[15]);

            f32x4 acc[4];
            #pragma unroll
            for (int mt = 0; mt < 4; ++mt) acc[mt] = (f32x4){0.f, 0.f, 0.f, 0.f};
            #pragma unroll
            for (int mt = 0; mt < 4; ++mt) {
                acc[mt] = mfma16(afr[mt][0], bfv0, acc[mt]);
                acc[mt] = mfma16(afr[mt][1], bfv1, acc[mt]);
                acc[mt] = mfma16(afr[mt][2], bfv2, acc[mt]);
                acc[mt] = mfma16(afr[mt][3], bfv3, acc[mt]);
            }
            #pragma unroll
            for (int k = 0; k < 16; ++k) aD[k] = acc[k >> 2][k & 3] * em[k];
        }

        // per-column renorm (column lives in lanes {nc, nc+16, nc+32, nc+48})
        float cm = aD[0];
        #pragma unroll
        for (int k = 1; k < 16; ++k) cm = fmaxf(cm, aD[k]);
        cm = fmaxf(cm, __shfl_xor(cm, 16, 64));
        cm = fmaxf(cm, __shfl_xor(cm, 32, 64));
        cm = fmaxf(cm, 1e-30f);
        float rc = __builtin_amdgcn_rcpf(cm);
        #pragma unroll
        for (int k = 0; k < 16; ++k) aD[k] *= rc;
        offs += __logf(cm);
    }

    // store S (bf16 truncate) row-major [row][col]; offsets per column
    unsigned short* Pp = wsP + ((size_t)blk << 12);
    #pragma unroll
    for (int c = 0; c < 4; ++c)
        #pragma unroll
        for (int r = 0; r < 4; ++r)
            Pp[(16 * c + 4 * q + r) * 64 + 16 * w + nc] =
                (unsigned short)(__float_as_uint(aD[4 * c + r]) >> 16);
    if (q == 0) wsO[(size_t)blk * 64 + 16 * w + nc] = offs;
}

// ---------------------------------------------------------------------------
// Phase 2: per-batch wave, 16 serial slice-matvecs with per-column offsets:
//   alpha <- S_ch · (alpha ⊙ exp(o - max o)),  Omega += max o + log(renorm)
// Gold score fused (r6-verified).
// ---------------------------------------------------------------------------
__global__ __launch_bounds__(64)
__attribute__((amdgpu_waves_per_eu(1, 1)))
void crf_combine(const unsigned short* __restrict__ wsP,
                 const float* __restrict__ wsO,
                 const float* __restrict__ feats,
                 const float* __restrict__ trans,
                 const int*   __restrict__ tags,
                 const float* __restrict__ masks,
                 float* __restrict__ out)
{
    const int b = blockIdx.x;
    const int L = threadIdx.x, nc = L & 15, q = L >> 4;

    float aD[16];
    #pragma unroll
    for (int k = 0; k < 16; ++k) aD[k] = 0.f;
    if (q == 0) aD[0] = 1.f;           // alpha0 = e_START, replicated columns
    float Omega = 0.f;

    for (int ch = 0; ch < NCH; ++ch) {
        const unsigned short* Pp = wsP + ((size_t)(b * NCH + ch) << 12);
        const float* op = wsO + (size_t)(b * NCH + ch) * 64;

        // per-column offsets at k = 16c+4q+r
        float o[16];
        #pragma unroll
        for (int c = 0; c < 4; ++c) {
            float4 ov = *(const float4*)(op + 16 * c + 4 * q);
            o[4*c+0] = ov.x; o[4*c+1] = ov.y; o[4*c+2] = ov.z; o[4*c+3] = ov.w;
        }
        float Om = o[0];
        #pragma unroll
        for (int k = 1; k < 16; ++k) Om = fmaxf(Om, o[k]);
        Om = fmaxf(Om, __shfl_xor(Om, 16, 64));
        Om = fmaxf(Om, __shfl_xor(Om, 32, 64));

        float wv[16];
        #pragma unroll
        for (int k = 0; k < 16; ++k) wv[k] = aD[k] * __expf(o[k] - Om);

        bf16x4 bfv0 = packT(wv[0],  wv[1],  wv[2],  wv[3]);
        bf16x4 bfv1 = packT(wv[4],  wv[5],  wv[6],  wv[7]);
        bf16x4 bfv2 = packT(wv[8],  wv[9],  wv[10], wv[11]);
        bf16x4 bfv3 = packT(wv[12], wv[13], wv[14], wv[15]);

        f32x4 acc[4];
        #pragma unroll
        for (int mt = 0; mt < 4; ++mt) acc[mt] = (f32x4){0.f, 0.f, 0.f, 0.f};
        #pragma unroll
        for (int mt = 0; mt < 4; ++mt) {
            const unsigned short* rowp = Pp + (16 * mt + nc) * 64 + 4 * q;
            bf16x4 a0 = __builtin_bit_cast(bf16x4, *(const uint2*)(rowp));
            bf16x4 a1 = __builtin_bit_cast(bf16x4, *(const uint2*)(rowp + 16));
            bf16x4 a2 = __builtin_bit_cast(bf16x4, *(const uint2*)(rowp + 32));
            bf16x4 a3 = __builtin_bit_cast(bf16x4, *(const uint2*)(rowp + 48));
            acc[mt] = mfma16(a0, bfv0, acc[mt]);
            acc[mt] = mfma16(a1, bfv1, acc[mt]);
            acc[mt] = mfma16(a2, bfv2, acc[mt]);
            acc[mt] = mfma16(a3, bfv3, acc[mt]);
        }

        float mx = acc[0][0];
        #pragma unroll
        for (int k = 1; k < 16; ++k) mx = fmaxf(mx, acc[k >> 2][k & 3]);
        mx = fmaxf(mx, __shfl_xor(mx, 16, 64));
        mx = fmaxf(mx, __shfl_xor(mx, 32, 64));
        mx = fmaxf(mx, 1e-30f);
        float rc = __builtin_amdgcn_rcpf(mx);
        #pragma unroll
        for (int k = 0; k < 16; ++k) aD[k] = acc[k >> 2][k & 3] * rc;
        Omega += Om + __logf(mx);
    }

    // fwd = Omega + log(sum_m alpha[m])
    float s = aD[0];
    #pragma unroll
    for (int k = 1; k < 16; ++k) s += aD[k];
    s += __shfl_xor(s, 16, 64);
    s += __shfl_xor(s, 32, 64);
    float fwd = Omega + __logf(s);

    // fused gold score
    const int*   tg = tags  + b * TT;
    const float* fb = feats + (size_t)b * TT * KK;
    const float* mp = masks + (size_t)b * TT;
    float g = 0.f;
    for (int t = 1 + L; t < TT; t += 64) {
        int ct = tg[t], pt = tg[t - 1];
        g += (trans[ct * KK + pt] + fb[(size_t)t * KK + ct]) * mp[t];
    }
    #pragma unroll
    for (int off = 1; off <= 32; off <<= 1) g += __shfl_xor(g, off, 64);

    if (L == 0) atomicAdd(out, (fwd - g) * (1.0f / (float)BB));
}

extern "C" void kernel_launch(void* const* d_in, const int* in_sizes, int n_in,
                              void* d_out, int out_size, void* d_ws, size_t ws_size,
                              hipStream_t stream) {
    const float* feats = (const float*)d_in[0];
    const float* trans = (const float*)d_in[1];
    const int*   tags  = (const int*)d_in[2];
    const float* masks = (const float*)d_in[3];
    float* out = (float*)d_out;

    unsigned short* wsP = (unsigned short*)d_ws;              // 4096 x 4096 bf16 = 33.5 MB
    float* wsO = (float*)(wsP + ((size_t)BB * NCH << 12));    // 4096 x 64 f32 = 1 MB

    hipMemsetAsync(out, 0, sizeof(float), stream);
    crf_scan<<<BB * NCH, 256, 0, stream>>>(feats, trans, masks, wsP, wsO);
    crf_combine<<<BB, 64, 0, stream>>>(wsP, wsO, feats, trans, tags, masks, out);
}